// Round 4
// baseline (118.535 us; speedup 1.0000x reference)
//
#include <hip/hip_runtime.h>
#include <hip/hip_bf16.h>
#include <cstdint>

#define DEV static __device__ __forceinline__

typedef float        v4f __attribute__((ext_vector_type(4)));
typedef float        v2f __attribute__((ext_vector_type(2)));
typedef short        v8s __attribute__((ext_vector_type(8)));
typedef unsigned int v4u __attribute__((ext_vector_type(4)));

static constexpr int N_ENT = 100000;
static constexpr int BATCH = 4096;

DEV unsigned short f2bf(float f) {
    __hip_bfloat16 h = __float2bfloat16(f);
    return __builtin_bit_cast(unsigned short, h);
}
DEV unsigned int pkbf(float lo, float hi) {
    return (unsigned)f2bf(lo) | ((unsigned)f2bf(hi) << 16);
}
DEV float bflo(unsigned int w) { return __uint_as_float(w << 16); }
DEV float bfhi(unsigned int w) { return __uint_as_float(w & 0xffff0000u); }
DEV v2f up2(unsigned int w) { return (v2f){bflo(w), bfhi(w)}; }

// ---------------- K0: R1b = bf16(rel @ W1[64:]); W2p/W1p packed into MFMA B-frag layout
__global__ void k0_prep(const float* __restrict__ rel, const float* __restrict__ W1,
                        const float* __restrict__ W2,
                        unsigned short* __restrict__ R1b, unsigned short* __restrict__ W2p,
                        unsigned short* __restrict__ W1p)
{
    const int gid = blockIdx.x * 256 + threadIdx.x;
    if (gid < 2048) {
        const int r = gid >> 6, j = gid & 63;
        float acc = 0.f;
        #pragma unroll 8
        for (int k = 0; k < 64; ++k)
            acc += rel[r * 64 + k] * W1[(64 + k) * 64 + j];
        R1b[gid] = f2bf(acc);
    } else if (gid < 2048 + 4096) {
        // Wp[((kk*4+tn)*64 + l)*8 + i] = bf16( W[(32kk + 8*(l>>4) + i)][16tn + (l&15)] )
        const int f = gid - 2048;
        const int i = f & 7, l = (f >> 3) & 63;
        const int tn = (f >> 9) & 3, kk = f >> 11;
        W2p[f] = f2bf(W2[(32 * kk + 8 * (l >> 4) + i) * 64 + 16 * tn + (l & 15)]);
    } else if (gid < 2048 + 8192) {
        const int f = gid - 6144;
        const int i = f & 7, l = (f >> 3) & 63;
        const int tn = (f >> 9) & 3, kk = f >> 11;
        W1p[f] = f2bf(W1[(32 * kk + 8 * (l >> 4) + i) * 64 + 16 * tn + (l & 15)]);
    }
}

// ---------------- K1: MFMA GEMM: E1 = bf16(emb @ W1[:64]); E0 = bf16(emb). 16 rows/wave.
__global__ void __launch_bounds__(256) k1_e1(const float* __restrict__ emb,
                                             const unsigned short* __restrict__ W1p,
                                             unsigned short* __restrict__ E1,
                                             unsigned short* __restrict__ E0)
{
    const int lane = threadIdx.x & 63;
    const int q = lane & 15, g = lane >> 4;
    const int wid = blockIdx.x * 4 + (threadIdx.x >> 6);
    const int e0 = wid * 16;
    if (e0 >= N_ENT) return;

    v8s af[2];
    #pragma unroll
    for (int kk = 0; kk < 2; ++kk) {
        const float* p = emb + (size_t)(e0 + q) * 64 + 32 * kk + 8 * g;
        const v4f x = *(const v4f*)p;
        const v4f y = *(const v4f*)(p + 4);
        v4u pk;
        pk[0] = pkbf(x[0], x[1]); pk[1] = pkbf(x[2], x[3]);
        pk[2] = pkbf(y[0], y[1]); pk[3] = pkbf(y[2], y[3]);
        af[kk] = __builtin_bit_cast(v8s, pk);
        *(v4u*)(E0 + (size_t)(e0 + q) * 64 + 32 * kk + 8 * g) = pk;
    }

    v4f acc[4];
    #pragma unroll
    for (int tn = 0; tn < 4; ++tn) acc[tn] = (v4f){0.f, 0.f, 0.f, 0.f};
    #pragma unroll
    for (int kk = 0; kk < 2; ++kk)
        #pragma unroll
        for (int tn = 0; tn < 4; ++tn) {
            const v8s bfr = *(const v8s*)(W1p + ((kk * 4 + tn) * 64 + lane) * 8);
            acc[tn] = __builtin_amdgcn_mfma_f32_16x16x32_bf16(af[kk], bfr, acc[tn], 0, 0, 0);
        }
    #pragma unroll
    for (int tn = 0; tn < 4; ++tn)
        #pragma unroll
        for (int i = 0; i < 4; ++i)
            E1[(size_t)(e0 + 4 * g + i) * 64 + 16 * tn + q] = f2bf(acc[tn][i]);
}

// ---------------- K2: fused attention + means + dot + sigmoid; pinned register prefetch
__global__ void __launch_bounds__(256, 4) k2_fused(
    const int* __restrict__ items,
    const int* __restrict__ user_h, const int* __restrict__ user_r, const int* __restrict__ user_t,
    const int* __restrict__ item_h, const int* __restrict__ item_r, const int* __restrict__ item_t,
    const float* __restrict__ emb, const unsigned short* __restrict__ E0,
    const unsigned short* __restrict__ E1,
    const unsigned short* __restrict__ R1b, const unsigned short* __restrict__ W2p,
    const float* __restrict__ W3, float* __restrict__ out)
{
    __shared__ float ws_w[4][64];   // softmax weights (incl 1/S)
    __shared__ float att_s[4][64];  // per-combo attention output
    __shared__ float mp[4][64];     // per-wave mean partials

    const int lane  = threadIdx.x & 63;
    const int b     = blockIdx.x;
    const int combo = threadIdx.x >> 6;        // 0:uL0 1:uL1 2:iL0 3:iL1
    const int layer = combo & 1;
    const int side  = combo >> 1, half = combo & 1;
    const int* Hp; const int* Rp; const int* Tp;
    if (combo < 2) { Hp = user_h; Rp = user_r; Tp = user_t; }
    else           { Hp = item_h; Rp = item_r; Tp = item_t; }
    const int base = (layer * BATCH + b) * 64;
    const int* H0p = (side ? item_h : user_h) + b * 64;   // layer-0 heads for mean

    const int q = lane & 15, g = lane >> 4;
    const int sub = lane & 7, grp = lane >> 3;

    // ---- indices
    int hidx[4], ridx[4];
    #pragma unroll
    for (int tm = 0; tm < 4; ++tm) {
        hidx[tm] = Hp[base + 16 * tm + q];
        ridx[tm] = Rp[base + 16 * tm + q];
    }
    const int tv = Tp[base + lane];
    int midx[4];
    #pragma unroll
    for (int it = 0; it < 4; ++it) midx[it] = H0p[32 * half + 8 * it + grp];

    // ---- issue gathers; post-barrier consumers get PINNED so loads aren't sunk
    v4u ev[4][2], rv[4][2];
    #pragma unroll
    for (int tm = 0; tm < 4; ++tm)
        #pragma unroll
        for (int kk = 0; kk < 2; ++kk) {
            ev[tm][kk] = *(const v4u*)(E1  + (size_t)hidx[tm] * 64 + 32 * kk + 8 * g);
            rv[tm][kk] = *(const v4u*)(R1b + (size_t)ridx[tm] * 64 + 32 * kk + 8 * g);
        }
    v4u e0v[8];
    #pragma unroll
    for (int it = 0; it < 8; ++it) {
        const int tr = __shfl(tv, 8 * it + grp);
        e0v[it] = *(const v4u*)(E0 + (size_t)tr * 64 + sub * 8);
    }
    v4u m0v[4];
    #pragma unroll
    for (int it = 0; it < 4; ++it)
        m0v[it] = *(const v4u*)(E0 + (size_t)midx[it] * 64 + sub * 8);
    float itemv = (combo == 0) ? emb[(size_t)items[b] * 64 + lane] : 0.f;

    #pragma unroll
    for (int it = 0; it < 8; ++it) asm volatile("" : "+v"(e0v[it]));
    #pragma unroll
    for (int it = 0; it < 4; ++it) asm volatile("" : "+v"(m0v[it]));
    asm volatile("" : "+v"(itemv));

    float w3v[4];
    #pragma unroll
    for (int tn = 0; tn < 4; ++tn) w3v[tn] = W3[16 * tn + q];

    // ---- MFMA: a2 = relu(relu(E1h + R1r) @ W2); logits p
    float p[4][4];
    #pragma unroll
    for (int tm = 0; tm < 4; ++tm) {
        v4f a4[4];
        #pragma unroll
        for (int tn = 0; tn < 4; ++tn) a4[tn] = (v4f){0.f, 0.f, 0.f, 0.f};
        #pragma unroll
        for (int kk = 0; kk < 2; ++kk) {
            v4u afu;
            #pragma unroll
            for (int w = 0; w < 4; ++w) {
                const unsigned int e = ev[tm][kk][w], r = rv[tm][kk][w];
                afu[w] = pkbf(fmaxf(bflo(e) + bflo(r), 0.f),
                              fmaxf(bfhi(e) + bfhi(r), 0.f));
            }
            const v8s af = __builtin_bit_cast(v8s, afu);
            #pragma unroll
            for (int tn = 0; tn < 4; ++tn) {
                const v8s bfr = *(const v8s*)(W2p + ((kk * 4 + tn) * 64 + lane) * 8);
                a4[tn] = __builtin_amdgcn_mfma_f32_16x16x32_bf16(af, bfr, a4[tn], 0, 0, 0);
            }
        }
        #pragma unroll
        for (int i = 0; i < 4; ++i) {
            float s = 0.f;
            #pragma unroll
            for (int tn = 0; tn < 4; ++tn)
                s += fmaxf(a4[tn][i], 0.f) * w3v[tn];
            p[tm][i] = s;
        }
    }
    #pragma unroll
    for (int m = 1; m <= 8; m <<= 1)
        #pragma unroll
        for (int tm = 0; tm < 4; ++tm)
            #pragma unroll
            for (int i = 0; i < 4; ++i)
                p[tm][i] += __shfl_xor(p[tm][i], m);

    // ---- sigmoid -> exp -> softmax sum (logits in [0,1], no max-shift needed)
    float ee[4][4];
    float sloc = 0.f;
    #pragma unroll
    for (int tm = 0; tm < 4; ++tm)
        #pragma unroll
        for (int i = 0; i < 4; ++i) {
            const float sg = 1.f / (1.f + __expf(-p[tm][i]));
            const float ex = __expf(sg);
            ee[tm][i] = ex;
            sloc += ex;
        }
    sloc += __shfl_xor(sloc, 16);
    sloc += __shfl_xor(sloc, 32);
    const float rS = 1.f / sloc;

    if (q == 0) {
        #pragma unroll
        for (int tm = 0; tm < 4; ++tm) {
            v4f wv;
            #pragma unroll
            for (int i = 0; i < 4; ++i) wv[i] = ee[tm][i] * rS;
            *(v4f*)&ws_w[combo][16 * tm + 4 * g] = wv;
        }
    }
    __syncthreads();

    // ---- weighted t-sum + hop-0 means from pinned registers (packed f32 math)
    v2f a2[4], m2[4];
    #pragma unroll
    for (int c = 0; c < 4; ++c) { a2[c] = (v2f){0.f, 0.f}; m2[c] = (v2f){0.f, 0.f}; }
    #pragma unroll
    for (int it = 0; it < 8; ++it) {
        const float w = ws_w[combo][8 * it + grp];
        const v2f wv = (v2f){w, w};
        const v4u e = e0v[it];
        #pragma unroll
        for (int c = 0; c < 4; ++c) a2[c] += wv * up2(e[c]);
    }
    #pragma unroll
    for (int it = 0; it < 4; ++it) {
        const v4u e = m0v[it];
        #pragma unroll
        for (int c = 0; c < 4; ++c) m2[c] += up2(e[c]);
    }
    #pragma unroll
    for (int m = 8; m <= 32; m <<= 1)
        #pragma unroll
        for (int c = 0; c < 4; ++c) {
            a2[c][0] += __shfl_xor(a2[c][0], m);
            a2[c][1] += __shfl_xor(a2[c][1], m);
            m2[c][0] += __shfl_xor(m2[c][0], m);
            m2[c][1] += __shfl_xor(m2[c][1], m);
        }
    if (lane < 8) {
        #pragma unroll
        for (int c = 0; c < 4; ++c) {
            att_s[combo][lane * 8 + 2 * c]     = a2[c][0];
            att_s[combo][lane * 8 + 2 * c + 1] = a2[c][1];
            mp[combo][lane * 8 + 2 * c]        = m2[c][0];
            mp[combo][lane * 8 + 2 * c + 1]    = m2[c][1];
        }
    }
    __syncthreads();

    // ---- final combine + dot + sigmoid (wave 0; item row already in itemv)
    if (threadIdx.x < 64) {
        const int j = lane;
        const float eu = att_s[0][j] + att_s[1][j] + (mp[0][j] + mp[1][j]) * (1.f / 64.f);
        const float evv = itemv + att_s[2][j] + att_s[3][j]
                        + (mp[2][j] + mp[3][j]) * (1.f / 64.f);
        float d = eu * evv;
        #pragma unroll
        for (int m = 1; m <= 32; m <<= 1) d += __shfl_xor(d, m);
        if (lane == 0) out[b] = 1.f / (1.f + __expf(-d));
    }
}

extern "C" void kernel_launch(void* const* d_in, const int* in_sizes, int n_in,
                              void* d_out, int out_size, void* d_ws, size_t ws_size,
                              hipStream_t stream)
{
    const int*   items  = (const int*)d_in[0];
    const int*   user_h = (const int*)d_in[1];
    const int*   user_r = (const int*)d_in[2];
    const int*   user_t = (const int*)d_in[3];
    const int*   item_h = (const int*)d_in[4];
    const int*   item_r = (const int*)d_in[5];
    const int*   item_t = (const int*)d_in[6];
    const float* emb    = (const float*)d_in[7];
    const float* rel    = (const float*)d_in[8];
    const float* W1     = (const float*)d_in[9];
    const float* W2     = (const float*)d_in[10];
    const float* W3     = (const float*)d_in[11];
    float* out = (float*)d_out;

    char* ws = (char*)d_ws;
    const size_t tb = (size_t)N_ENT * 64 * 2;           // 12.8 MB per table
    unsigned short* E0  = (unsigned short*)ws;
    unsigned short* E1  = (unsigned short*)(ws + tb);
    unsigned short* R1b = (unsigned short*)(ws + 2 * tb);
    unsigned short* W2p = (unsigned short*)(ws + 2 * tb + 4096);
    unsigned short* W1p = (unsigned short*)(ws + 2 * tb + 4096 + 8192);

    hipLaunchKernelGGL(k0_prep, dim3(40), dim3(256), 0, stream, rel, W1, W2, R1b, W2p, W1p);
    hipLaunchKernelGGL(k1_e1, dim3((6250 + 3) / 4), dim3(256), 0, stream, emb, W1p, E1, E0);
    hipLaunchKernelGGL(k2_fused, dim3(BATCH), dim3(256), 0, stream,
                       items, user_h, user_r, user_t, item_h, item_r, item_t,
                       emb, E0, E1, R1b, W2p, W3, out);
}

// Round 5
// 94.510 us; speedup vs baseline: 1.2542x; 1.2542x over previous
//
#include <hip/hip_runtime.h>
#include <hip/hip_bf16.h>
#include <cstdint>

#define DEV static __device__ __forceinline__

typedef float        v4f __attribute__((ext_vector_type(4)));
typedef float        v2f __attribute__((ext_vector_type(2)));
typedef short        v8s __attribute__((ext_vector_type(8)));
typedef unsigned int v4u __attribute__((ext_vector_type(4)));

static constexpr int N_ENT = 100000;
static constexpr int BATCH = 4096;

DEV unsigned short f2bf(float f) {
    __hip_bfloat16 h = __float2bfloat16(f);
    return __builtin_bit_cast(unsigned short, h);
}
DEV unsigned int pkbf(float lo, float hi) {
    return (unsigned)f2bf(lo) | ((unsigned)f2bf(hi) << 16);
}
DEV float bflo(unsigned int w) { return __uint_as_float(w << 16); }
DEV float bfhi(unsigned int w) { return __uint_as_float(w & 0xffff0000u); }
DEV v2f up2(unsigned int w) { return (v2f){bflo(w), bfhi(w)}; }

// ---------------- K0: R1b = bf16(rel @ W1[64:]); W2p/W1p packed into MFMA B-frag layout
__global__ void k0_prep(const float* __restrict__ rel, const float* __restrict__ W1,
                        const float* __restrict__ W2,
                        unsigned short* __restrict__ R1b, unsigned short* __restrict__ W2p,
                        unsigned short* __restrict__ W1p)
{
    const int gid = blockIdx.x * 256 + threadIdx.x;
    if (gid < 2048) {
        const int r = gid >> 6, j = gid & 63;
        float acc = 0.f;
        #pragma unroll 8
        for (int k = 0; k < 64; ++k)
            acc += rel[r * 64 + k] * W1[(64 + k) * 64 + j];
        R1b[gid] = f2bf(acc);
    } else if (gid < 2048 + 4096) {
        // Wp[((kk*4+tn)*64 + l)*8 + i] = bf16( W[(32kk + 8*(l>>4) + i)][16tn + (l&15)] )
        const int f = gid - 2048;
        const int i = f & 7, l = (f >> 3) & 63;
        const int tn = (f >> 9) & 3, kk = f >> 11;
        W2p[f] = f2bf(W2[(32 * kk + 8 * (l >> 4) + i) * 64 + 16 * tn + (l & 15)]);
    } else if (gid < 2048 + 8192) {
        const int f = gid - 6144;
        const int i = f & 7, l = (f >> 3) & 63;
        const int tn = (f >> 9) & 3, kk = f >> 11;
        W1p[f] = f2bf(W1[(32 * kk + 8 * (l >> 4) + i) * 64 + 16 * tn + (l & 15)]);
    }
}

// ---------------- K1: MFMA GEMM: E1 = bf16(emb @ W1[:64]); E0 = bf16(emb). 16 rows/wave.
__global__ void __launch_bounds__(256) k1_e1(const float* __restrict__ emb,
                                             const unsigned short* __restrict__ W1p,
                                             unsigned short* __restrict__ E1,
                                             unsigned short* __restrict__ E0)
{
    const int lane = threadIdx.x & 63;
    const int q = lane & 15, g = lane >> 4;
    const int wid = blockIdx.x * 4 + (threadIdx.x >> 6);
    const int e0 = wid * 16;
    if (e0 >= N_ENT) return;

    v8s af[2];
    #pragma unroll
    for (int kk = 0; kk < 2; ++kk) {
        const float* p = emb + (size_t)(e0 + q) * 64 + 32 * kk + 8 * g;
        const v4f x = *(const v4f*)p;
        const v4f y = *(const v4f*)(p + 4);
        v4u pk;
        pk[0] = pkbf(x[0], x[1]); pk[1] = pkbf(x[2], x[3]);
        pk[2] = pkbf(y[0], y[1]); pk[3] = pkbf(y[2], y[3]);
        af[kk] = __builtin_bit_cast(v8s, pk);
        *(v4u*)(E0 + (size_t)(e0 + q) * 64 + 32 * kk + 8 * g) = pk;
    }

    v4f acc[4];
    #pragma unroll
    for (int tn = 0; tn < 4; ++tn) acc[tn] = (v4f){0.f, 0.f, 0.f, 0.f};
    #pragma unroll
    for (int kk = 0; kk < 2; ++kk)
        #pragma unroll
        for (int tn = 0; tn < 4; ++tn) {
            const v8s bfr = *(const v8s*)(W1p + ((kk * 4 + tn) * 64 + lane) * 8);
            acc[tn] = __builtin_amdgcn_mfma_f32_16x16x32_bf16(af[kk], bfr, acc[tn], 0, 0, 0);
        }
    #pragma unroll
    for (int tn = 0; tn < 4; ++tn)
        #pragma unroll
        for (int i = 0; i < 4; ++i)
            E1[(size_t)(e0 + 4 * g + i) * 64 + 16 * tn + q] = f2bf(acc[tn][i]);
}

// ---------------- K2: fused attention + means + dot + sigmoid; pinned register prefetch
__global__ void __launch_bounds__(256) k2_fused(
    const int* __restrict__ items,
    const int* __restrict__ user_h, const int* __restrict__ user_r, const int* __restrict__ user_t,
    const int* __restrict__ item_h, const int* __restrict__ item_r, const int* __restrict__ item_t,
    const float* __restrict__ emb, const unsigned short* __restrict__ E0,
    const unsigned short* __restrict__ E1,
    const unsigned short* __restrict__ R1b, const unsigned short* __restrict__ W2p,
    const float* __restrict__ W3, float* __restrict__ out)
{
    __shared__ float ws_w[4][64];   // softmax weights (wave-private exchange, no barrier)
    __shared__ float att_s[4][64];  // per-combo attention output
    __shared__ float mp[4][64];     // per-wave mean partials

    const int lane  = threadIdx.x & 63;
    const int b     = blockIdx.x;
    const int combo = threadIdx.x >> 6;        // 0:uL0 1:uL1 2:iL0 3:iL1
    const int layer = combo & 1;
    const int side  = combo >> 1, half = combo & 1;
    const int* Hp; const int* Rp; const int* Tp;
    if (combo < 2) { Hp = user_h; Rp = user_r; Tp = user_t; }
    else           { Hp = item_h; Rp = item_r; Tp = item_t; }
    const int base = (layer * BATCH + b) * 64;
    const int* H0p = (side ? item_h : user_h) + b * 64;   // layer-0 heads for mean

    const int q = lane & 15, g = lane >> 4;
    const int sub = lane & 7, grp = lane >> 3;

    // ---- indices
    int hidx[4], ridx[4];
    #pragma unroll
    for (int tm = 0; tm < 4; ++tm) {
        hidx[tm] = Hp[base + 16 * tm + q];
        ridx[tm] = Rp[base + 16 * tm + q];
    }
    const int tv = Tp[base + lane];
    int midx[4];
    #pragma unroll
    for (int it = 0; it < 4; ++it) midx[it] = H0p[32 * half + 8 * it + grp];

    // ---- issue gathers; post-softmax consumers get PINNED so loads aren't sunk
    v4u ev[4][2], rv[4][2];
    #pragma unroll
    for (int tm = 0; tm < 4; ++tm)
        #pragma unroll
        for (int kk = 0; kk < 2; ++kk) {
            ev[tm][kk] = *(const v4u*)(E1  + (size_t)hidx[tm] * 64 + 32 * kk + 8 * g);
            rv[tm][kk] = *(const v4u*)(R1b + (size_t)ridx[tm] * 64 + 32 * kk + 8 * g);
        }
    v4u e0v[8];
    #pragma unroll
    for (int it = 0; it < 8; ++it) {
        const int tr = __shfl(tv, 8 * it + grp);
        e0v[it] = *(const v4u*)(E0 + (size_t)tr * 64 + sub * 8);
    }
    v4u m0v[4];
    #pragma unroll
    for (int it = 0; it < 4; ++it)
        m0v[it] = *(const v4u*)(E0 + (size_t)midx[it] * 64 + sub * 8);
    float itemv = (combo == 0) ? emb[(size_t)items[b] * 64 + lane] : 0.f;

    #pragma unroll
    for (int it = 0; it < 8; ++it) asm volatile("" : "+v"(e0v[it]));
    #pragma unroll
    for (int it = 0; it < 4; ++it) asm volatile("" : "+v"(m0v[it]));
    asm volatile("" : "+v"(itemv));

    float w3v[4];
    #pragma unroll
    for (int tn = 0; tn < 4; ++tn) w3v[tn] = W3[16 * tn + q];

    // ---- MFMA: a2 = relu(relu(E1h + R1r) @ W2); logits p
    float p[4][4];
    #pragma unroll
    for (int tm = 0; tm < 4; ++tm) {
        v4f a4[4];
        #pragma unroll
        for (int tn = 0; tn < 4; ++tn) a4[tn] = (v4f){0.f, 0.f, 0.f, 0.f};
        #pragma unroll
        for (int kk = 0; kk < 2; ++kk) {
            v4u afu;
            #pragma unroll
            for (int w = 0; w < 4; ++w) {
                const unsigned int e = ev[tm][kk][w], r = rv[tm][kk][w];
                afu[w] = pkbf(fmaxf(bflo(e) + bflo(r), 0.f),
                              fmaxf(bfhi(e) + bfhi(r), 0.f));
            }
            const v8s af = __builtin_bit_cast(v8s, afu);
            #pragma unroll
            for (int tn = 0; tn < 4; ++tn) {
                const v8s bfr = *(const v8s*)(W2p + ((kk * 4 + tn) * 64 + lane) * 8);
                a4[tn] = __builtin_amdgcn_mfma_f32_16x16x32_bf16(af, bfr, a4[tn], 0, 0, 0);
            }
        }
        #pragma unroll
        for (int i = 0; i < 4; ++i) {
            float s = 0.f;
            #pragma unroll
            for (int tn = 0; tn < 4; ++tn)
                s += fmaxf(a4[tn][i], 0.f) * w3v[tn];
            p[tm][i] = s;
        }
    }
    #pragma unroll
    for (int m = 1; m <= 8; m <<= 1)
        #pragma unroll
        for (int tm = 0; tm < 4; ++tm)
            #pragma unroll
            for (int i = 0; i < 4; ++i)
                p[tm][i] += __shfl_xor(p[tm][i], m);

    // ---- sigmoid -> exp -> softmax sum (logits in [0,1], no max-shift needed)
    float ee[4][4];
    float sloc = 0.f;
    #pragma unroll
    for (int tm = 0; tm < 4; ++tm)
        #pragma unroll
        for (int i = 0; i < 4; ++i) {
            const float sg = 1.f / (1.f + __expf(-p[tm][i]));
            const float ex = __expf(sg);
            ee[tm][i] = ex;
            sloc += ex;
        }
    sloc += __shfl_xor(sloc, 16);
    sloc += __shfl_xor(sloc, 32);
    const float rS = 1.f / sloc;

    // ---- wave-private weight exchange through LDS (same wave writes & reads: no barrier)
    if (q == 0) {
        #pragma unroll
        for (int tm = 0; tm < 4; ++tm) {
            v4f wv;
            #pragma unroll
            for (int i = 0; i < 4; ++i) wv[i] = ee[tm][i] * rS;
            *(v4f*)&ws_w[combo][16 * tm + 4 * g] = wv;
        }
    }

    // ---- weighted t-sum + hop-0 means from pinned registers (packed f32 math)
    v2f a2[4], m2[4];
    #pragma unroll
    for (int c = 0; c < 4; ++c) { a2[c] = (v2f){0.f, 0.f}; m2[c] = (v2f){0.f, 0.f}; }
    #pragma unroll
    for (int it = 0; it < 8; ++it) {
        const float w = ws_w[combo][8 * it + grp];
        const v2f wv = (v2f){w, w};
        const v4u e = e0v[it];
        #pragma unroll
        for (int c = 0; c < 4; ++c) a2[c] += wv * up2(e[c]);
    }
    #pragma unroll
    for (int it = 0; it < 4; ++it) {
        const v4u e = m0v[it];
        #pragma unroll
        for (int c = 0; c < 4; ++c) m2[c] += up2(e[c]);
    }
    #pragma unroll
    for (int m = 8; m <= 32; m <<= 1)
        #pragma unroll
        for (int c = 0; c < 4; ++c) {
            a2[c][0] += __shfl_xor(a2[c][0], m);
            a2[c][1] += __shfl_xor(a2[c][1], m);
            m2[c][0] += __shfl_xor(m2[c][0], m);
            m2[c][1] += __shfl_xor(m2[c][1], m);
        }
    if (lane < 8) {
        #pragma unroll
        for (int c = 0; c < 4; ++c) {
            att_s[combo][lane * 8 + 2 * c]     = a2[c][0];
            att_s[combo][lane * 8 + 2 * c + 1] = a2[c][1];
            mp[combo][lane * 8 + 2 * c]        = m2[c][0];
            mp[combo][lane * 8 + 2 * c + 1]    = m2[c][1];
        }
    }
    __syncthreads();

    // ---- final combine + dot + sigmoid (wave 0; item row already in itemv)
    if (threadIdx.x < 64) {
        const int j = lane;
        const float eu = att_s[0][j] + att_s[1][j] + (mp[0][j] + mp[1][j]) * (1.f / 64.f);
        const float evv = itemv + att_s[2][j] + att_s[3][j]
                        + (mp[2][j] + mp[3][j]) * (1.f / 64.f);
        float d = eu * evv;
        #pragma unroll
        for (int m = 1; m <= 32; m <<= 1) d += __shfl_xor(d, m);
        if (lane == 0) out[b] = 1.f / (1.f + __expf(-d));
    }
}

extern "C" void kernel_launch(void* const* d_in, const int* in_sizes, int n_in,
                              void* d_out, int out_size, void* d_ws, size_t ws_size,
                              hipStream_t stream)
{
    const int*   items  = (const int*)d_in[0];
    const int*   user_h = (const int*)d_in[1];
    const int*   user_r = (const int*)d_in[2];
    const int*   user_t = (const int*)d_in[3];
    const int*   item_h = (const int*)d_in[4];
    const int*   item_r = (const int*)d_in[5];
    const int*   item_t = (const int*)d_in[6];
    const float* emb    = (const float*)d_in[7];
    const float* rel    = (const float*)d_in[8];
    const float* W1     = (const float*)d_in[9];
    const float* W2     = (const float*)d_in[10];
    const float* W3     = (const float*)d_in[11];
    float* out = (float*)d_out;

    char* ws = (char*)d_ws;
    const size_t tb = (size_t)N_ENT * 64 * 2;           // 12.8 MB per table
    unsigned short* E0  = (unsigned short*)ws;
    unsigned short* E1  = (unsigned short*)(ws + tb);
    unsigned short* R1b = (unsigned short*)(ws + 2 * tb);
    unsigned short* W2p = (unsigned short*)(ws + 2 * tb + 4096);
    unsigned short* W1p = (unsigned short*)(ws + 2 * tb + 4096 + 8192);

    hipLaunchKernelGGL(k0_prep, dim3(40), dim3(256), 0, stream, rel, W1, W2, R1b, W2p, W1p);
    hipLaunchKernelGGL(k1_e1, dim3((6250 + 3) / 4), dim3(256), 0, stream, emb, W1p, E1, E0);
    hipLaunchKernelGGL(k2_fused, dim3(BATCH), dim3(256), 0, stream,
                       items, user_h, user_r, user_t, item_h, item_r, item_t,
                       emb, E0, E1, R1b, W2p, W3, out);
}

// Round 6
// 79.276 us; speedup vs baseline: 1.4952x; 1.1922x over previous
//
#include <hip/hip_runtime.h>
#include <hip/hip_bf16.h>
#include <cstdint>

#define DEV static __device__ __forceinline__

typedef float        v4f __attribute__((ext_vector_type(4)));
typedef float        v2f __attribute__((ext_vector_type(2)));
typedef short        v8s __attribute__((ext_vector_type(8)));
typedef unsigned int v4u __attribute__((ext_vector_type(4)));

static constexpr int N_ENT = 100000;
static constexpr int BATCH = 4096;

DEV unsigned short f2bf(float f) {
    __hip_bfloat16 h = __float2bfloat16(f);
    return __builtin_bit_cast(unsigned short, h);
}
DEV unsigned int pkbf(float lo, float hi) {
    return (unsigned)f2bf(lo) | ((unsigned)f2bf(hi) << 16);
}
DEV float bflo(unsigned int w) { return __uint_as_float(w << 16); }
DEV float bfhi(unsigned int w) { return __uint_as_float(w & 0xffff0000u); }
DEV v2f up2(unsigned int w) { return (v2f){bflo(w), bfhi(w)}; }

// async global->LDS, 16 B per lane; LDS dest = uniform base + lane*16
DEV void glds16(const void* g, void* l) {
    __builtin_amdgcn_global_load_lds(
        (const __attribute__((address_space(1))) unsigned int*)g,
        (__attribute__((address_space(3))) unsigned int*)l, 16, 0, 0);
}

// ---------------- K0: R1b = bf16(rel @ W1[64:]); W2p/W1p packed into MFMA B-frag layout
__global__ void k0_prep(const float* __restrict__ rel, const float* __restrict__ W1,
                        const float* __restrict__ W2,
                        unsigned short* __restrict__ R1b, unsigned short* __restrict__ W2p,
                        unsigned short* __restrict__ W1p)
{
    const int gid = blockIdx.x * 256 + threadIdx.x;
    if (gid < 2048) {
        const int r = gid >> 6, j = gid & 63;
        float acc = 0.f;
        #pragma unroll 8
        for (int k = 0; k < 64; ++k)
            acc += rel[r * 64 + k] * W1[(64 + k) * 64 + j];
        R1b[gid] = f2bf(acc);
    } else if (gid < 2048 + 4096) {
        // Wp[((kk*4+tn)*64 + l)*8 + i] = bf16( W[(32kk + 8*(l>>4) + i)][16tn + (l&15)] )
        const int f = gid - 2048;
        const int i = f & 7, l = (f >> 3) & 63;
        const int tn = (f >> 9) & 3, kk = f >> 11;
        W2p[f] = f2bf(W2[(32 * kk + 8 * (l >> 4) + i) * 64 + 16 * tn + (l & 15)]);
    } else if (gid < 2048 + 8192) {
        const int f = gid - 6144;
        const int i = f & 7, l = (f >> 3) & 63;
        const int tn = (f >> 9) & 3, kk = f >> 11;
        W1p[f] = f2bf(W1[(32 * kk + 8 * (l >> 4) + i) * 64 + 16 * tn + (l & 15)]);
    }
}

// ---------------- K1: MFMA GEMM: E1 = bf16(emb @ W1[:64]); E0 = bf16(emb). 16 rows/wave.
__global__ void __launch_bounds__(256) k1_e1(const float* __restrict__ emb,
                                             const unsigned short* __restrict__ W1p,
                                             unsigned short* __restrict__ E1,
                                             unsigned short* __restrict__ E0)
{
    const int lane = threadIdx.x & 63;
    const int q = lane & 15, g = lane >> 4;
    const int wid = blockIdx.x * 4 + (threadIdx.x >> 6);
    const int e0 = wid * 16;
    if (e0 >= N_ENT) return;

    v8s af[2];
    #pragma unroll
    for (int kk = 0; kk < 2; ++kk) {
        const float* p = emb + (size_t)(e0 + q) * 64 + 32 * kk + 8 * g;
        const v4f x = *(const v4f*)p;
        const v4f y = *(const v4f*)(p + 4);
        v4u pk;
        pk[0] = pkbf(x[0], x[1]); pk[1] = pkbf(x[2], x[3]);
        pk[2] = pkbf(y[0], y[1]); pk[3] = pkbf(y[2], y[3]);
        af[kk] = __builtin_bit_cast(v8s, pk);
        *(v4u*)(E0 + (size_t)(e0 + q) * 64 + 32 * kk + 8 * g) = pk;
    }

    v4f acc[4];
    #pragma unroll
    for (int tn = 0; tn < 4; ++tn) acc[tn] = (v4f){0.f, 0.f, 0.f, 0.f};
    #pragma unroll
    for (int kk = 0; kk < 2; ++kk)
        #pragma unroll
        for (int tn = 0; tn < 4; ++tn) {
            const v8s bfr = *(const v8s*)(W1p + ((kk * 4 + tn) * 64 + lane) * 8);
            acc[tn] = __builtin_amdgcn_mfma_f32_16x16x32_bf16(af[kk], bfr, acc[tn], 0, 0, 0);
        }
    #pragma unroll
    for (int tn = 0; tn < 4; ++tn)
        #pragma unroll
        for (int i = 0; i < 4; ++i)
            E1[(size_t)(e0 + 4 * g + i) * 64 + 16 * tn + q] = f2bf(acc[tn][i]);
}

// ---------------- K2: fused attention + means + dot + sigmoid; async LDS-staged prefetch
__global__ void __launch_bounds__(256) k2_fused(
    const int* __restrict__ items,
    const int* __restrict__ user_h, const int* __restrict__ user_r, const int* __restrict__ user_t,
    const int* __restrict__ item_h, const int* __restrict__ item_r, const int* __restrict__ item_t,
    const float* __restrict__ emb, const unsigned short* __restrict__ E0,
    const unsigned short* __restrict__ E1,
    const unsigned short* __restrict__ R1b, const unsigned short* __restrict__ W2p,
    const float* __restrict__ W3, float* __restrict__ out)
{
    __shared__ float ws_w[4][64];   // softmax weights (wave-private exchange, no barrier)
    __shared__ float att_s[4][64];  // per-combo attention output
    __shared__ float mp[4][64];     // per-wave mean partials
    __shared__ __align__(16) unsigned char e0s[4][8192];  // staged t-rows  (8 KiB/wave)
    __shared__ __align__(16) unsigned char m0s[4][4096];  // staged mean rows (4 KiB/wave)

    const int lane  = threadIdx.x & 63;
    const int b     = blockIdx.x;
    const int combo = threadIdx.x >> 6;        // 0:uL0 1:uL1 2:iL0 3:iL1
    const int layer = combo & 1;
    const int side  = combo >> 1, half = combo & 1;
    const int* Hp; const int* Rp; const int* Tp;
    if (combo < 2) { Hp = user_h; Rp = user_r; Tp = user_t; }
    else           { Hp = item_h; Rp = item_r; Tp = item_t; }
    const int base = (layer * BATCH + b) * 64;
    const int* H0p = (side ? item_h : user_h) + b * 64;   // layer-0 heads for mean

    const int q = lane & 15, g = lane >> 4;
    const int sub = lane & 7, grp = lane >> 3;

    // ---- indices
    int hidx[4], ridx[4];
    #pragma unroll
    for (int tm = 0; tm < 4; ++tm) {
        hidx[tm] = Hp[base + 16 * tm + q];
        ridx[tm] = Rp[base + 16 * tm + q];
    }
    const int tv = Tp[base + lane];
    int midx[4];
    #pragma unroll
    for (int it = 0; it < 4; ++it) midx[it] = H0p[32 * half + 8 * it + grp];

    // ---- register gathers consumed in the MFMA phase (issued first: oldest in vmcnt queue)
    v4u ev[4][2], rv[4][2];
    #pragma unroll
    for (int tm = 0; tm < 4; ++tm)
        #pragma unroll
        for (int kk = 0; kk < 2; ++kk) {
            ev[tm][kk] = *(const v4u*)(E1  + (size_t)hidx[tm] * 64 + 32 * kk + 8 * g);
            rv[tm][kk] = *(const v4u*)(R1b + (size_t)ridx[tm] * 64 + 32 * kk + 8 * g);
        }

    // ---- async LDS staging for post-softmax consumers (no VGPR cost, no forced wait)
    #pragma unroll
    for (int it = 0; it < 8; ++it) {
        const int tr = __shfl(tv, 8 * it + grp);
        glds16(E0 + (size_t)tr * 64 + sub * 8, &e0s[combo][it * 1024]);
    }
    #pragma unroll
    for (int it = 0; it < 4; ++it)
        glds16(E0 + (size_t)midx[it] * 64 + sub * 8, &m0s[combo][it * 1024]);
    __builtin_amdgcn_sched_barrier(0);   // pin issue point; no data wait implied

    float w3v[4];
    #pragma unroll
    for (int tn = 0; tn < 4; ++tn) w3v[tn] = W3[16 * tn + q];

    // ---- MFMA: a2 = relu(relu(E1h + R1r) @ W2); logits p
    float p[4][4];
    #pragma unroll
    for (int tm = 0; tm < 4; ++tm) {
        v4f a4[4];
        #pragma unroll
        for (int tn = 0; tn < 4; ++tn) a4[tn] = (v4f){0.f, 0.f, 0.f, 0.f};
        #pragma unroll
        for (int kk = 0; kk < 2; ++kk) {
            v4u afu;
            #pragma unroll
            for (int w = 0; w < 4; ++w) {
                const unsigned int e = ev[tm][kk][w], r = rv[tm][kk][w];
                afu[w] = pkbf(fmaxf(bflo(e) + bflo(r), 0.f),
                              fmaxf(bfhi(e) + bfhi(r), 0.f));
            }
            const v8s af = __builtin_bit_cast(v8s, afu);
            #pragma unroll
            for (int tn = 0; tn < 4; ++tn) {
                const v8s bfr = *(const v8s*)(W2p + ((kk * 4 + tn) * 64 + lane) * 8);
                a4[tn] = __builtin_amdgcn_mfma_f32_16x16x32_bf16(af, bfr, a4[tn], 0, 0, 0);
            }
        }
        #pragma unroll
        for (int i = 0; i < 4; ++i) {
            float s = 0.f;
            #pragma unroll
            for (int tn = 0; tn < 4; ++tn)
                s += fmaxf(a4[tn][i], 0.f) * w3v[tn];
            p[tm][i] = s;
        }
    }
    #pragma unroll
    for (int m = 1; m <= 8; m <<= 1)
        #pragma unroll
        for (int tm = 0; tm < 4; ++tm)
            #pragma unroll
            for (int i = 0; i < 4; ++i)
                p[tm][i] += __shfl_xor(p[tm][i], m);

    // ---- sigmoid -> exp -> softmax sum (logits in [0,1], no max-shift needed)
    float ee[4][4];
    float sloc = 0.f;
    #pragma unroll
    for (int tm = 0; tm < 4; ++tm)
        #pragma unroll
        for (int i = 0; i < 4; ++i) {
            const float sg = 1.f / (1.f + __expf(-p[tm][i]));
            const float ex = __expf(sg);
            ee[tm][i] = ex;
            sloc += ex;
        }
    sloc += __shfl_xor(sloc, 16);
    sloc += __shfl_xor(sloc, 32);
    const float rS = 1.f / sloc;

    // ---- wave-private weight exchange through LDS (same wave writes & reads: no barrier)
    if (q == 0) {
        #pragma unroll
        for (int tm = 0; tm < 4; ++tm) {
            v4f wv;
            #pragma unroll
            for (int i = 0; i < 4; ++i) wv[i] = ee[tm][i] * rS;
            *(v4f*)&ws_w[combo][16 * tm + 4 * g] = wv;
        }
    }

    // ---- staged gathers have had the whole MFMA+softmax phase to land
    asm volatile("s_waitcnt vmcnt(0)" ::: "memory");
    __builtin_amdgcn_sched_barrier(0);

    // ---- weighted t-sum + hop-0 means from staged LDS (packed f32 math)
    v2f a2[4], m2[4];
    #pragma unroll
    for (int c = 0; c < 4; ++c) { a2[c] = (v2f){0.f, 0.f}; m2[c] = (v2f){0.f, 0.f}; }
    #pragma unroll
    for (int it = 0; it < 8; ++it) {
        const float w = ws_w[combo][8 * it + grp];
        const v2f wv = (v2f){w, w};
        const v4u e = *(const v4u*)&e0s[combo][it * 1024 + lane * 16];
        #pragma unroll
        for (int c = 0; c < 4; ++c) a2[c] += wv * up2(e[c]);
    }
    #pragma unroll
    for (int it = 0; it < 4; ++it) {
        const v4u e = *(const v4u*)&m0s[combo][it * 1024 + lane * 16];
        #pragma unroll
        for (int c = 0; c < 4; ++c) m2[c] += up2(e[c]);
    }
    #pragma unroll
    for (int m = 8; m <= 32; m <<= 1)
        #pragma unroll
        for (int c = 0; c < 4; ++c) {
            a2[c][0] += __shfl_xor(a2[c][0], m);
            a2[c][1] += __shfl_xor(a2[c][1], m);
            m2[c][0] += __shfl_xor(m2[c][0], m);
            m2[c][1] += __shfl_xor(m2[c][1], m);
        }
    if (lane < 8) {
        #pragma unroll
        for (int c = 0; c < 4; ++c) {
            att_s[combo][lane * 8 + 2 * c]     = a2[c][0];
            att_s[combo][lane * 8 + 2 * c + 1] = a2[c][1];
            mp[combo][lane * 8 + 2 * c]        = m2[c][0];
            mp[combo][lane * 8 + 2 * c + 1]    = m2[c][1];
        }
    }
    __syncthreads();

    // ---- final combine + dot + sigmoid (wave 0)
    if (threadIdx.x < 64) {
        const int j = lane;
        const float itemv = emb[(size_t)items[b] * 64 + j];
        const float eu = att_s[0][j] + att_s[1][j] + (mp[0][j] + mp[1][j]) * (1.f / 64.f);
        const float evv = itemv + att_s[2][j] + att_s[3][j]
                        + (mp[2][j] + mp[3][j]) * (1.f / 64.f);
        float d = eu * evv;
        #pragma unroll
        for (int m = 1; m <= 32; m <<= 1) d += __shfl_xor(d, m);
        if (lane == 0) out[b] = 1.f / (1.f + __expf(-d));
    }
}

extern "C" void kernel_launch(void* const* d_in, const int* in_sizes, int n_in,
                              void* d_out, int out_size, void* d_ws, size_t ws_size,
                              hipStream_t stream)
{
    const int*   items  = (const int*)d_in[0];
    const int*   user_h = (const int*)d_in[1];
    const int*   user_r = (const int*)d_in[2];
    const int*   user_t = (const int*)d_in[3];
    const int*   item_h = (const int*)d_in[4];
    const int*   item_r = (const int*)d_in[5];
    const int*   item_t = (const int*)d_in[6];
    const float* emb    = (const float*)d_in[7];
    const float* rel    = (const float*)d_in[8];
    const float* W1     = (const float*)d_in[9];
    const float* W2     = (const float*)d_in[10];
    const float* W3     = (const float*)d_in[11];
    float* out = (float*)d_out;

    char* ws = (char*)d_ws;
    const size_t tb = (size_t)N_ENT * 64 * 2;           // 12.8 MB per table
    unsigned short* E0  = (unsigned short*)ws;
    unsigned short* E1  = (unsigned short*)(ws + tb);
    unsigned short* R1b = (unsigned short*)(ws + 2 * tb);
    unsigned short* W2p = (unsigned short*)(ws + 2 * tb + 4096);
    unsigned short* W1p = (unsigned short*)(ws + 2 * tb + 4096 + 8192);

    hipLaunchKernelGGL(k0_prep, dim3(40), dim3(256), 0, stream, rel, W1, W2, R1b, W2p, W1p);
    hipLaunchKernelGGL(k1_e1, dim3((6250 + 3) / 4), dim3(256), 0, stream, emb, W1p, E1, E0);
    hipLaunchKernelGGL(k2_fused, dim3(BATCH), dim3(256), 0, stream,
                       items, user_h, user_r, user_t, item_h, item_r, item_t,
                       emb, E0, E1, R1b, W2p, W3, out);
}